// Round 2
// baseline (694.901 us; speedup 1.0000x reference)
//
#include <hip/hip_runtime.h>
#include <hip/hip_bf16.h>
#include <math.h>

typedef __attribute__((ext_vector_type(8))) short short8;
typedef __attribute__((ext_vector_type(4))) short short4_t;
typedef __attribute__((ext_vector_type(4))) float f32x4;

#define Bb 2
#define Tt 2048
#define Hh 16
#define Dd 128
#define Cc 2048
#define Ff 6144

__device__ __forceinline__ void gload_lds16(const void* g, void* l) {
  __builtin_amdgcn_global_load_lds(
      (const __attribute__((address_space(1))) void*)g,
      (__attribute__((address_space(3))) void*)l, 16, 0, 0);
}

// fp32 -> bf16 cast, 4 elements/thread, vectorized.
__global__ __launch_bounds__(256) void cast_f32_bf16(
    const float* __restrict__ in, __hip_bfloat16* __restrict__ out, int n4)
{
  int i = blockIdx.x * 256 + threadIdx.x;
  if (i >= n4) return;
  float4 v = ((const float4*)in)[i];
  __hip_bfloat16 tmp[4] = {__float2bfloat16(v.x), __float2bfloat16(v.y),
                           __float2bfloat16(v.z), __float2bfloat16(v.w)};
  ((short4_t*)out)[i] = *(const short4_t*)tmp;
}

__device__ __forceinline__ void store_out(__hip_bfloat16* p, float v) { *p = __float2bfloat16(v); }
__device__ __forceinline__ void store_out(float* p, float v) { *p = v; }

// C (MxN) = A (MxK, row-major) * B^T  (B given NxK row-major). bf16 in, fp32 accum.
// grid: (N/128, M/128), block 256. m97 structure: 128x128x32 tile, global_load_lds w16.
template <typename OutT>
__global__ __launch_bounds__(256) void gemm_bt(
    const __hip_bfloat16* __restrict__ A,
    const __hip_bfloat16* __restrict__ Bm,
    OutT* __restrict__ Cm,
    int K, int N)
{
  __shared__ __align__(16) __hip_bfloat16 As[128 * 32];
  __shared__ __align__(16) __hip_bfloat16 Bs[128 * 32];
  const int tid  = threadIdx.x;
  const int wave = tid >> 6;
  const int lane = tid & 63;
  const int quad = lane >> 4;
  const int l16  = lane & 15;
  const int bm = blockIdx.y * 128;
  const int bn = blockIdx.x * 128;
  const int wm = (wave >> 1) * 64;
  const int wn = (wave & 1) * 64;

  f32x4 acc[4][4];
#pragma unroll
  for (int i = 0; i < 4; i++)
#pragma unroll
    for (int j = 0; j < 4; j++)
#pragma unroll
      for (int r = 0; r < 4; r++) acc[i][j][r] = 0.f;

  const int srow = lane >> 2;        // 0..15 (row within 16-row chunk)
  const int scol = (lane & 3) * 8;   // 0,8,16,24 (bf16 elements)

  for (int k0 = 0; k0 < K; k0 += 32) {
#pragma unroll
    for (int c = 0; c < 2; c++) {
      int r0 = (wave * 2 + c) * 16;  // wave-uniform
      gload_lds16(A  + (size_t)(bm + r0 + srow) * K + k0 + scol, As + r0 * 32);
      gload_lds16(Bm + (size_t)(bn + r0 + srow) * K + k0 + scol, Bs + r0 * 32);
    }
    __syncthreads();
    short8 af[4], bf[4];
#pragma unroll
    for (int i = 0; i < 4; i++)
      af[i] = *(const short8*)(As + (wm + i * 16 + l16) * 32 + quad * 8);
#pragma unroll
    for (int j = 0; j < 4; j++)
      bf[j] = *(const short8*)(Bs + (wn + j * 16 + l16) * 32 + quad * 8);
#pragma unroll
    for (int i = 0; i < 4; i++)
#pragma unroll
      for (int j = 0; j < 4; j++)
        acc[i][j] = __builtin_amdgcn_mfma_f32_16x16x32_bf16(af[i], bf[j], acc[i][j], 0, 0, 0);
    __syncthreads();
  }

#pragma unroll
  for (int i = 0; i < 4; i++)
#pragma unroll
    for (int j = 0; j < 4; j++)
#pragma unroll
      for (int r = 0; r < 4; r++) {
        int gm = bm + wm + i * 16 + quad * 4 + r;
        int gn = bn + wn + j * 16 + l16;
        store_out(Cm + (size_t)gm * N + gn, acc[i][j][r]);
      }
}

// In-place RoPE on q,k halves of qkv (4096 x 6144). One thread per (which,b,t,h,d<64) pair.
__global__ __launch_bounds__(256) void rope_qk(__hip_bfloat16* __restrict__ qkv)
{
  int tid = blockIdx.x * 256 + threadIdx.x;   // 0 .. 8388607
  int d = tid & 63;
  int h = (tid >> 6) & 15;
  int t = (tid >> 10) & 2047;
  int bw = tid >> 21;
  int b = bw & 1, which = bw >> 1;            // which 0=q, 1=k
  size_t base = (size_t)(b * Tt + t) * Ff + which * 2048 + h * Dd + d;
  // inv_freq = 10000^(-d/64)
  float inv = expf(-(float)d * (9.210340371976184f / 64.0f));
  float ang = (float)t * inv;
  float c = cosf(ang), s = sinf(ang);
  float x1 = __bfloat162float(qkv[base]);
  float x2 = __bfloat162float(qkv[base + 64]);
  qkv[base]      = __float2bfloat16(x1 * c - x2 * s);
  qkv[base + 64] = __float2bfloat16(x2 * c + x1 * s);
}

// v (from qkv buffer, (b,t,h,d)) -> vt (b,h,d,t). grid (64, 32).
__global__ __launch_bounds__(256) void transpose_v(
    const __hip_bfloat16* __restrict__ qkv, __hip_bfloat16* __restrict__ vt)
{
  __shared__ __hip_bfloat16 tile[64 * 65];
  int bh = blockIdx.y;
  int dt = blockIdx.x >> 5;   // 0..1  (64-wide d tile)
  int tt = blockIdx.x & 31;   // 0..31 (64-wide t tile)
  int b = bh >> 4, h = bh & 15;
  const __hip_bfloat16* src = qkv + (size_t)(b * Tt + tt * 64) * Ff + 4096 + h * Dd + dt * 64;
#pragma unroll
  for (int i = 0; i < 16; i++) {
    int lin = i * 256 + threadIdx.x;
    int tl = lin >> 6, dc = lin & 63;
    tile[tl * 65 + dc] = src[(size_t)tl * Ff + dc];
  }
  __syncthreads();
  __hip_bfloat16* dst = vt + ((size_t)bh * Dd + dt * 64) * Tt + tt * 64;
#pragma unroll
  for (int i = 0; i < 16; i++) {
    int lin = i * 256 + threadIdx.x;
    int dr = lin >> 6, tc = lin & 63;
    dst[(size_t)dr * Tt + tc] = tile[tc * 65 + dr];
  }
}

// Flash attention, causal. grid (32 q-tiles, 32 bh), block 256 (4 waves x 16 q-rows).
__global__ __launch_bounds__(256) void flash_attn(
    const __hip_bfloat16* __restrict__ qkv,
    const __hip_bfloat16* __restrict__ vt,
    __hip_bfloat16* __restrict__ yat)
{
  __shared__ __align__(16) __hip_bfloat16 Ks[64 * 128];   // [n_seq][d]
  __shared__ __align__(16) __hip_bfloat16 Vs[128 * 64];   // [d][n_seq]
  __shared__ __align__(16) __hip_bfloat16 Ps[4 * 16 * 64];// per-wave [16][64]
  const int tid  = threadIdx.x;
  const int wave = tid >> 6;
  const int lane = tid & 63;
  const int quad = lane >> 4;
  const int l16  = lane & 15;
  const int qi = blockIdx.x;       // q tile (64 rows)
  const int bh = blockIdx.y;
  const int b = bh >> 4, h = bh & 15;
  const int qm0 = qi * 64;
  const float scale = 0.08838834764831845f;  // 1/sqrt(128)

  short8 qf[4];
  {
    int tq = qm0 + wave * 16 + l16;
    const __hip_bfloat16* qrow = qkv + (size_t)(b * Tt + tq) * Ff + h * Dd;
#pragma unroll
    for (int kc = 0; kc < 4; kc++)
      qf[kc] = *(const short8*)(qrow + kc * 32 + quad * 8);
  }
  const __hip_bfloat16* kbase = qkv + (size_t)b * Tt * Ff + 2048 + h * Dd; // + t*Ff + d
  const __hip_bfloat16* vbase = vt + (size_t)bh * Dd * Tt;                 // + d*Tt + t

  f32x4 oacc[8];
#pragma unroll
  for (int jd = 0; jd < 8; jd++)
#pragma unroll
    for (int r = 0; r < 4; r++) oacc[jd][r] = 0.f;
  float mrow[4], lrow[4];
#pragma unroll
  for (int r = 0; r < 4; r++) { mrow[r] = -INFINITY; lrow[r] = 0.f; }

  for (int kt = 0; kt <= qi; ++kt) {
#pragma unroll
    for (int c = 0; c < 4; c++) {
      int chunk = wave * 4 + c;  // wave-uniform, 0..15
      int krow = chunk * 4 + (lane >> 4);
      int kcol = (lane & 15) * 8;
      gload_lds16(kbase + (size_t)(kt * 64 + krow) * Ff + kcol, Ks + chunk * 512);
      int vrow = chunk * 8 + (lane >> 3);
      int vcol = (lane & 7) * 8;
      gload_lds16(vbase + (size_t)vrow * Tt + kt * 64 + vcol, Vs + chunk * 512);
    }
    __syncthreads();

    // S = Q K^T for this wave's 16 rows x 64 cols
    f32x4 sacc[4];
#pragma unroll
    for (int j = 0; j < 4; j++)
#pragma unroll
      for (int r = 0; r < 4; r++) sacc[j][r] = 0.f;
#pragma unroll
    for (int j = 0; j < 4; j++)
#pragma unroll
      for (int kc = 0; kc < 4; kc++) {
        short8 kf = *(const short8*)(Ks + (j * 16 + l16) * 128 + kc * 32 + quad * 8);
        sacc[j] = __builtin_amdgcn_mfma_f32_16x16x32_bf16(qf[kc], kf, sacc[j], 0, 0, 0);
      }

    float sv[4][4];
#pragma unroll
    for (int j = 0; j < 4; j++)
#pragma unroll
      for (int r = 0; r < 4; r++) {
        float v = sacc[j][r] * scale;
        if (kt == qi) {
          int kg = kt * 64 + j * 16 + l16;
          int qg = qm0 + wave * 16 + quad * 4 + r;
          if (kg > qg) v = -INFINITY;
        }
        sv[j][r] = v;
      }

    float mnew[4];
#pragma unroll
    for (int r = 0; r < 4; r++) {
      float m = sv[0][r];
#pragma unroll
      for (int j = 1; j < 4; j++) m = fmaxf(m, sv[j][r]);
      mnew[r] = m;
    }
#pragma unroll
    for (int off = 1; off < 16; off <<= 1)
#pragma unroll
      for (int r = 0; r < 4; r++)
        mnew[r] = fmaxf(mnew[r], __shfl_xor(mnew[r], off, 64));

    float alpha[4];
#pragma unroll
    for (int r = 0; r < 4; r++) {
      float mi = fmaxf(mrow[r], mnew[r]);
      alpha[r] = __expf(mrow[r] - mi);
      mrow[r] = mi;
    }

    float rs[4] = {0.f, 0.f, 0.f, 0.f};
#pragma unroll
    for (int j = 0; j < 4; j++)
#pragma unroll
      for (int r = 0; r < 4; r++) {
        float p = __expf(sv[j][r] - mrow[r]);
        rs[r] += p;
        Ps[(wave * 16 + quad * 4 + r) * 64 + j * 16 + l16] = __float2bfloat16(p);
      }
#pragma unroll
    for (int off = 1; off < 16; off <<= 1)
#pragma unroll
      for (int r = 0; r < 4; r++)
        rs[r] += __shfl_xor(rs[r], off, 64);
#pragma unroll
    for (int r = 0; r < 4; r++) lrow[r] = lrow[r] * alpha[r] + rs[r];

#pragma unroll
    for (int jd = 0; jd < 8; jd++)
#pragma unroll
      for (int r = 0; r < 4; r++) oacc[jd][r] *= alpha[r];

#pragma unroll
    for (int k2 = 0; k2 < 2; k2++) {
      short8 pf = *(const short8*)(Ps + (wave * 16 + l16) * 64 + k2 * 32 + quad * 8);
#pragma unroll
      for (int jd = 0; jd < 8; jd++) {
        short8 vf = *(const short8*)(Vs + (jd * 16 + l16) * 64 + k2 * 32 + quad * 8);
        oacc[jd] = __builtin_amdgcn_mfma_f32_16x16x32_bf16(pf, vf, oacc[jd], 0, 0, 0);
      }
    }
    __syncthreads();
  }

  float linv[4];
#pragma unroll
  for (int r = 0; r < 4; r++) linv[r] = 1.f / lrow[r];
#pragma unroll
  for (int jd = 0; jd < 8; jd++)
#pragma unroll
    for (int r = 0; r < 4; r++) {
      int trow = qm0 + wave * 16 + quad * 4 + r;
      yat[(size_t)(b * Tt + trow) * Cc + h * Dd + jd * 16 + l16] =
          __float2bfloat16(oacc[jd][r] * linv[r]);
    }
}

extern "C" void kernel_launch(void* const* d_in, const int* in_sizes, int n_in,
                              void* d_out, int out_size, void* d_ws, size_t ws_size,
                              hipStream_t stream) {
  (void)in_sizes; (void)n_in; (void)out_size; (void)ws_size;
  const float* x_f      = (const float*)d_in[0];
  const float* w_qkv_f  = (const float*)d_in[1];
  const float* w_proj_f = (const float*)d_in[2];
  float* out = (float*)d_out;

  char* ws = (char*)d_ws;
  __hip_bfloat16* qkv = (__hip_bfloat16*)ws;                      // 4096*6144*2  = 50331648 B
  __hip_bfloat16* vt  = (__hip_bfloat16*)(ws + 50331648);         // 16 MiB
  __hip_bfloat16* yat = (__hip_bfloat16*)(ws + 67108864);         // 16 MiB
  __hip_bfloat16* xb  = (__hip_bfloat16*)(ws + 83886080);         // 16 MiB
  __hip_bfloat16* wqb = (__hip_bfloat16*)(ws + 100663296);        // 24 MiB
  __hip_bfloat16* wpb = (__hip_bfloat16*)(ws + 125829120);        // 8 MiB -> 128 MiB total

  // 0. cast fp32 inputs -> bf16
  cast_f32_bf16<<<8192, 256, 0, stream>>>(x_f, xb, 2097152);
  cast_f32_bf16<<<12288, 256, 0, stream>>>(w_qkv_f, wqb, 3145728);
  cast_f32_bf16<<<4096, 256, 0, stream>>>(w_proj_f, wpb, 1048576);

  // 1. qkv = x @ w_qkv^T   (M=4096, N=6144, K=2048)
  gemm_bt<__hip_bfloat16><<<dim3(48, 32), 256, 0, stream>>>(xb, wqb, qkv, 2048, 6144);
  // 2. RoPE in place on q,k halves
  rope_qk<<<32768, 256, 0, stream>>>(qkv);
  // 3. v -> vt (b,h,d,t)
  transpose_v<<<dim3(64, 32), 256, 0, stream>>>(qkv, vt);
  // 4. flash attention -> yat (b,t,c)
  flash_attn<<<dim3(32, 32), 256, 0, stream>>>(qkv, vt, yat);
  // 5. out = yat @ w_proj^T  (M=4096, N=2048, K=2048) -> fp32 out
  gemm_bt<float><<<dim3(16, 32), 256, 0, stream>>>(yat, wpb, out, 2048, 2048);
}

// Round 3
// 478.349 us; speedup vs baseline: 1.4527x; 1.4527x over previous
//
#include <hip/hip_runtime.h>
#include <hip/hip_bf16.h>
#include <math.h>

typedef __attribute__((ext_vector_type(8))) short short8;
typedef __attribute__((ext_vector_type(4))) short short4_t;
typedef __attribute__((ext_vector_type(4))) float f32x4;

#define Bb 2
#define Tt 2048
#define Hh 16
#define Dd 128
#define Cc 2048
#define Ff 6144

__device__ __forceinline__ void gload_lds16(const void* g, void* l) {
  __builtin_amdgcn_global_load_lds(
      (const __attribute__((address_space(1))) void*)g,
      (__attribute__((address_space(3))) void*)l, 16, 0, 0);
}

// fp32 -> bf16 cast, 4 elements/thread, vectorized.
__global__ __launch_bounds__(256) void cast_f32_bf16(
    const float* __restrict__ in, __hip_bfloat16* __restrict__ out, int n4)
{
  int i = blockIdx.x * 256 + threadIdx.x;
  if (i >= n4) return;
  float4 v = ((const float4*)in)[i];
  __hip_bfloat16 tmp[4] = {__float2bfloat16(v.x), __float2bfloat16(v.y),
                           __float2bfloat16(v.z), __float2bfloat16(v.w)};
  ((short4_t*)out)[i] = *(const short4_t*)tmp;
}

__device__ __forceinline__ void store_out(__hip_bfloat16* p, float v) { *p = __float2bfloat16(v); }
__device__ __forceinline__ void store_out(float* p, float v) { *p = v; }

// C (MxN) = A (MxK, row-major) * B^T  (B given NxK row-major). bf16 in, fp32 accum.
template <typename OutT>
__global__ __launch_bounds__(256) void gemm_bt(
    const __hip_bfloat16* __restrict__ A,
    const __hip_bfloat16* __restrict__ Bm,
    OutT* __restrict__ Cm,
    int K, int N)
{
  __shared__ __align__(16) __hip_bfloat16 As[128 * 32];
  __shared__ __align__(16) __hip_bfloat16 Bs[128 * 32];
  const int tid  = threadIdx.x;
  const int wave = tid >> 6;
  const int lane = tid & 63;
  const int quad = lane >> 4;
  const int l16  = lane & 15;
  const int bm = blockIdx.y * 128;
  const int bn = blockIdx.x * 128;
  const int wm = (wave >> 1) * 64;
  const int wn = (wave & 1) * 64;

  f32x4 acc[4][4];
#pragma unroll
  for (int i = 0; i < 4; i++)
#pragma unroll
    for (int j = 0; j < 4; j++)
#pragma unroll
      for (int r = 0; r < 4; r++) acc[i][j][r] = 0.f;

  const int srow = lane >> 2;
  const int scol = (lane & 3) * 8;

  for (int k0 = 0; k0 < K; k0 += 32) {
#pragma unroll
    for (int c = 0; c < 2; c++) {
      int r0 = (wave * 2 + c) * 16;
      gload_lds16(A  + (size_t)(bm + r0 + srow) * K + k0 + scol, As + r0 * 32);
      gload_lds16(Bm + (size_t)(bn + r0 + srow) * K + k0 + scol, Bs + r0 * 32);
    }
    __syncthreads();
    short8 af[4], bf[4];
#pragma unroll
    for (int i = 0; i < 4; i++)
      af[i] = *(const short8*)(As + (wm + i * 16 + l16) * 32 + quad * 8);
#pragma unroll
    for (int j = 0; j < 4; j++)
      bf[j] = *(const short8*)(Bs + (wn + j * 16 + l16) * 32 + quad * 8);
#pragma unroll
    for (int i = 0; i < 4; i++)
#pragma unroll
      for (int j = 0; j < 4; j++)
        acc[i][j] = __builtin_amdgcn_mfma_f32_16x16x32_bf16(af[i], bf[j], acc[i][j], 0, 0, 0);
    __syncthreads();
  }

#pragma unroll
  for (int i = 0; i < 4; i++)
#pragma unroll
    for (int j = 0; j < 4; j++)
#pragma unroll
      for (int r = 0; r < 4; r++) {
        int gm = bm + wm + i * 16 + quad * 4 + r;
        int gn = bn + wn + j * 16 + l16;
        store_out(Cm + (size_t)gm * N + gn, acc[i][j][r]);
      }
}

// In-place RoPE on q,k halves of qkv.
__global__ __launch_bounds__(256) void rope_qk(__hip_bfloat16* __restrict__ qkv)
{
  int tid = blockIdx.x * 256 + threadIdx.x;
  int d = tid & 63;
  int h = (tid >> 6) & 15;
  int t = (tid >> 10) & 2047;
  int bw = tid >> 21;
  int b = bw & 1, which = bw >> 1;
  size_t base = (size_t)(b * Tt + t) * Ff + which * 2048 + h * Dd + d;
  float inv = expf(-(float)d * (9.210340371976184f / 64.0f));
  float ang = (float)t * inv;
  float c = cosf(ang), s = sinf(ang);
  float x1 = __bfloat162float(qkv[base]);
  float x2 = __bfloat162float(qkv[base + 64]);
  qkv[base]      = __float2bfloat16(x1 * c - x2 * s);
  qkv[base + 64] = __float2bfloat16(x2 * c + x1 * s);
}

// v (from qkv buffer, (b,t,h,d)) -> vt (b,h,d,t).
__global__ __launch_bounds__(256) void transpose_v(
    const __hip_bfloat16* __restrict__ qkv, __hip_bfloat16* __restrict__ vt)
{
  __shared__ __hip_bfloat16 tile[64 * 65];
  int bh = blockIdx.y;
  int dt = blockIdx.x >> 5;
  int tt = blockIdx.x & 31;
  int b = bh >> 4, h = bh & 15;
  const __hip_bfloat16* src = qkv + (size_t)(b * Tt + tt * 64) * Ff + 4096 + h * Dd + dt * 64;
#pragma unroll
  for (int i = 0; i < 16; i++) {
    int lin = i * 256 + threadIdx.x;
    int tl = lin >> 6, dc = lin & 63;
    tile[tl * 65 + dc] = src[(size_t)tl * Ff + dc];
  }
  __syncthreads();
  __hip_bfloat16* dst = vt + ((size_t)bh * Dd + dt * 64) * Tt + tt * 64;
#pragma unroll
  for (int i = 0; i < 16; i++) {
    int lin = i * 256 + threadIdx.x;
    int dr = lin >> 6, tc = lin & 63;
    dst[(size_t)dr * Tt + tc] = tile[tc * 65 + dr];
  }
}

// Flash attention v2: 128-row Q tiles, paired causal scheduling, software-pipelined
// staging with raw s_barrier + manual vmcnt (no vmcnt(0) drains in steady state).
// Grid: 256 flat blocks; block = (pair p = id>>5, bh = id&31); block processes
// q-tiles {p, 15-p} sequentially (34 k-iterations total -> perfect balance).
// LDS: Ks dbuf 32K + Vs 16K + Ps (padded granules) 8.5K = 57856 B.
__global__ __launch_bounds__(256) void flash_attn2(
    const __hip_bfloat16* __restrict__ qkv,
    const __hip_bfloat16* __restrict__ vt,
    __hip_bfloat16* __restrict__ yat)
{
  __shared__ __align__(16) __hip_bfloat16 KsBuf[2][8192];
  __shared__ __align__(16) __hip_bfloat16 VsBuf[8192];
  __shared__ __align__(16) __hip_bfloat16 PsBuf[4 * 1088];
  const int tid  = threadIdx.x;
  const int wave = tid >> 6;
  const int lane = tid & 63;
  const int quad = lane >> 4;
  const int l16  = lane & 15;
  const int bh    = blockIdx.x & 31;
  const int pairp = blockIdx.x >> 5;   // 0..7
  const int b = bh >> 4, h = bh & 15;
  const float scale = 0.08838834764831845f;  // 1/sqrt(128)

  const char* kbase = (const char*)(qkv + (size_t)b * Tt * Ff + 2048 + h * Dd);
  const char* vbase = (const char*)(vt + (size_t)bh * Dd * Tt);
  __hip_bfloat16* Pw = PsBuf + wave * 1088;
  const int srow = lane & 15;   // staging: row within 16-row group
  const int scol = lane >> 4;   // staging: 16B sub-column

#pragma unroll 1
  for (int half = 0; half < 2; ++half) {
    const int qi = half ? (15 - pairp) : pairp;
    const int qm0 = qi * 128;
    const int niter = 2 * qi + 2;

    // Q fragments for this tile (2 sub-tiles of 16 rows per wave)
    short8 qf[2][4];
#pragma unroll
    for (int mt = 0; mt < 2; mt++) {
      const __hip_bfloat16* qrow =
          qkv + (size_t)(b * Tt + qm0 + wave * 32 + mt * 16 + l16) * Ff + h * Dd;
#pragma unroll
      for (int kc = 0; kc < 4; kc++)
        qf[mt][kc] = *(const short8*)(qrow + kc * 32 + quad * 8);
    }

    // stage K(0) -> buf 0 (granule order: chunk*512 + lane*8 elems)
#pragma unroll
    for (int c = 0; c < 4; c++) {
      int chunk = wave * 4 + c;
      int j = chunk >> 2, kc = chunk & 3;
      const char* src = kbase + (size_t)(j * 16 + srow) * (Ff * 2) + kc * 64 + scol * 16;
      gload_lds16(src, KsBuf[0] + chunk * 512);
    }

    f32x4 oacc[2][8];
#pragma unroll
    for (int mt = 0; mt < 2; mt++)
#pragma unroll
      for (int jd = 0; jd < 8; jd++)
#pragma unroll
        for (int r = 0; r < 4; r++) oacc[mt][jd][r] = 0.f;
    float mrow[2][4], lrow[2][4];
#pragma unroll
    for (int mt = 0; mt < 2; mt++)
#pragma unroll
      for (int r = 0; r < 4; r++) { mrow[mt][r] = -INFINITY; lrow[mt][r] = 0.f; }

#pragma unroll 1
    for (int kt = 0; kt < niter; ++kt) {
      __builtin_amdgcn_s_barrier();                      // A: prev iter fully done
      // stage V(kt) -> Vs (single buffer; safe after barrier A)
#pragma unroll
      for (int c = 0; c < 4; c++) {
        int chunk = wave * 4 + c;
        int jd = chunk >> 1, k2 = chunk & 1;
        const char* src = vbase + (size_t)(jd * 16 + srow) * (Tt * 2) + kt * 128 + k2 * 64 + scol * 16;
        gload_lds16(src, VsBuf + chunk * 512);
      }
      if (kt + 1 < niter) {
        // stage K(kt+1) -> other buf
#pragma unroll
        for (int c = 0; c < 4; c++) {
          int chunk = wave * 4 + c;
          int j = chunk >> 2, kc = chunk & 3;
          const char* src = kbase + (size_t)((kt + 1) * 64 + j * 16 + srow) * (Ff * 2) + kc * 64 + scol * 16;
          gload_lds16(src, KsBuf[(kt + 1) & 1] + chunk * 512);
        }
        __builtin_amdgcn_s_waitcnt(0xF78);  // vmcnt(8): K(kt) landed (V(kt)+K(kt+1) in flight)
      } else {
        __builtin_amdgcn_s_waitcnt(0xF74);  // vmcnt(4): K(kt) landed (V(kt) in flight)
      }
      __builtin_amdgcn_s_barrier();                      // B: K(kt) visible to all waves

      const __hip_bfloat16* KsB = KsBuf[kt & 1];
      const bool diag = (kt >= 2 * qi);
      float pv1[4][4];                                   // mt=1 P values, written after PV0

#pragma unroll
      for (int mt = 0; mt < 2; mt++) {
        // S = Q K^T : 16 rows x 64 cols
        f32x4 sacc[4];
#pragma unroll
        for (int j = 0; j < 4; j++)
#pragma unroll
          for (int r = 0; r < 4; r++) sacc[j][r] = 0.f;
#pragma unroll
        for (int j = 0; j < 4; j++)
#pragma unroll
          for (int kc = 0; kc < 4; kc++) {
            short8 kf = *(const short8*)(KsB + (j * 4 + kc) * 512 + lane * 8);
            sacc[j] = __builtin_amdgcn_mfma_f32_16x16x32_bf16(qf[mt][kc], kf, sacc[j], 0, 0, 0);
          }
        float sv[4][4];
#pragma unroll
        for (int j = 0; j < 4; j++)
#pragma unroll
          for (int r = 0; r < 4; r++) {
            float v = sacc[j][r] * scale;
            if (diag) {
              int kg = kt * 64 + j * 16 + l16;
              int qg = qm0 + wave * 32 + mt * 16 + quad * 4 + r;
              if (kg > qg) v = -INFINITY;
            }
            sv[j][r] = v;
          }
        float mnew[4];
#pragma unroll
        for (int r = 0; r < 4; r++) {
          float m = fmaxf(fmaxf(sv[0][r], sv[1][r]), fmaxf(sv[2][r], sv[3][r]));
          mnew[r] = m;
        }
#pragma unroll
        for (int off = 1; off < 16; off <<= 1)
#pragma unroll
          for (int r = 0; r < 4; r++)
            mnew[r] = fmaxf(mnew[r], __shfl_xor(mnew[r], off, 64));
        float alpha[4];
#pragma unroll
        for (int r = 0; r < 4; r++) {
          float mi = fmaxf(mrow[mt][r], mnew[r]);
          alpha[r] = __expf(mrow[mt][r] - mi);
          mrow[mt][r] = mi;
        }
        float rs[4] = {0.f, 0.f, 0.f, 0.f};
#pragma unroll
        for (int j = 0; j < 4; j++)
#pragma unroll
          for (int r = 0; r < 4; r++) {
            float p = __expf(sv[j][r] - mrow[mt][r]);
            rs[r] += p;
            if (mt == 0)
              Pw[(j * 2 + (l16 >> 3)) * 136 + (quad * 4 + r) * 8 + (l16 & 7)] = __float2bfloat16(p);
            else
              pv1[j][r] = p;
          }
#pragma unroll
        for (int off = 1; off < 16; off <<= 1)
#pragma unroll
          for (int r = 0; r < 4; r++)
            rs[r] += __shfl_xor(rs[r], off, 64);
#pragma unroll
        for (int r = 0; r < 4; r++) lrow[mt][r] = lrow[mt][r] * alpha[r] + rs[r];
#pragma unroll
        for (int jd = 0; jd < 8; jd++)
#pragma unroll
          for (int r = 0; r < 4; r++) oacc[mt][jd][r] *= alpha[r];
      }

      if (kt + 1 < niter) {
        __builtin_amdgcn_s_waitcnt(0xF74);  // vmcnt(4): V(kt) landed (K(kt+1) in flight)
      } else {
        __builtin_amdgcn_s_waitcnt(0xF70);  // vmcnt(0)
      }
      __builtin_amdgcn_s_barrier();                      // C: V(kt) visible to all waves

      // PV for mt=0 (P already in LDS)
#pragma unroll
      for (int k2 = 0; k2 < 2; k2++) {
        short8 pf = *(const short8*)(Pw + (k2 * 4 + quad) * 136 + l16 * 8);
#pragma unroll
        for (int jd = 0; jd < 8; jd++) {
          short8 vf = *(const short8*)(VsBuf + (jd * 2 + k2) * 512 + lane * 8);
          oacc[0][jd] = __builtin_amdgcn_mfma_f32_16x16x32_bf16(pf, vf, oacc[0][jd], 0, 0, 0);
        }
      }
      // write P(mt=1) (wave-private; lgkm ordering protects vs pf reads above)
#pragma unroll
      for (int j = 0; j < 4; j++)
#pragma unroll
        for (int r = 0; r < 4; r++)
          Pw[(j * 2 + (l16 >> 3)) * 136 + (quad * 4 + r) * 8 + (l16 & 7)] = __float2bfloat16(pv1[j][r]);
#pragma unroll
      for (int k2 = 0; k2 < 2; k2++) {
        short8 pf = *(const short8*)(Pw + (k2 * 4 + quad) * 136 + l16 * 8);
#pragma unroll
        for (int jd = 0; jd < 8; jd++) {
          short8 vf = *(const short8*)(VsBuf + (jd * 2 + k2) * 512 + lane * 8);
          oacc[1][jd] = __builtin_amdgcn_mfma_f32_16x16x32_bf16(pf, vf, oacc[1][jd], 0, 0, 0);
        }
      }
    }

    // epilogue: O / l -> yat
#pragma unroll
    for (int mt = 0; mt < 2; mt++) {
      float linv[4];
#pragma unroll
      for (int r = 0; r < 4; r++) linv[r] = 1.f / lrow[mt][r];
#pragma unroll
      for (int jd = 0; jd < 8; jd++)
#pragma unroll
        for (int r = 0; r < 4; r++) {
          int trow = qm0 + wave * 32 + mt * 16 + quad * 4 + r;
          yat[(size_t)(b * Tt + trow) * Cc + h * Dd + jd * 16 + l16] =
              __float2bfloat16(oacc[mt][jd][r] * linv[r]);
        }
    }
  }
}

extern "C" void kernel_launch(void* const* d_in, const int* in_sizes, int n_in,
                              void* d_out, int out_size, void* d_ws, size_t ws_size,
                              hipStream_t stream) {
  (void)in_sizes; (void)n_in; (void)out_size; (void)ws_size;
  const float* x_f      = (const float*)d_in[0];
  const float* w_qkv_f  = (const float*)d_in[1];
  const float* w_proj_f = (const float*)d_in[2];
  float* out = (float*)d_out;

  char* ws = (char*)d_ws;
  __hip_bfloat16* qkv = (__hip_bfloat16*)ws;                      // 48 MiB
  __hip_bfloat16* vt  = (__hip_bfloat16*)(ws + 50331648);         // 16 MiB
  __hip_bfloat16* yat = (__hip_bfloat16*)(ws + 67108864);         // 16 MiB
  __hip_bfloat16* xb  = (__hip_bfloat16*)(ws + 83886080);         // 16 MiB
  __hip_bfloat16* wqb = (__hip_bfloat16*)(ws + 100663296);        // 24 MiB
  __hip_bfloat16* wpb = (__hip_bfloat16*)(ws + 125829120);        // 8 MiB

  cast_f32_bf16<<<8192, 256, 0, stream>>>(x_f, xb, 2097152);
  cast_f32_bf16<<<12288, 256, 0, stream>>>(w_qkv_f, wqb, 3145728);
  cast_f32_bf16<<<4096, 256, 0, stream>>>(w_proj_f, wpb, 1048576);

  gemm_bt<__hip_bfloat16><<<dim3(48, 32), 256, 0, stream>>>(xb, wqb, qkv, 2048, 6144);
  rope_qk<<<32768, 256, 0, stream>>>(qkv);
  transpose_v<<<dim3(64, 32), 256, 0, stream>>>(qkv, vt);
  flash_attn2<<<256, 256, 0, stream>>>(qkv, vt, yat);
  gemm_bt<float><<<dim3(16, 32), 256, 0, stream>>>(yat, wpb, out, 2048, 2048);
}

// Round 4
// 462.529 us; speedup vs baseline: 1.5024x; 1.0342x over previous
//
#include <hip/hip_runtime.h>
#include <hip/hip_bf16.h>
#include <math.h>

typedef __attribute__((ext_vector_type(8))) short short8;
typedef __attribute__((ext_vector_type(4))) short short4_t;
typedef __attribute__((ext_vector_type(4))) float f32x4;

#define Bb 2
#define Tt 2048
#define Hh 16
#define Dd 128
#define Cc 2048
#define Ff 6144

__device__ __forceinline__ void gload_lds16(const void* g, void* l) {
  __builtin_amdgcn_global_load_lds(
      (const __attribute__((address_space(1))) void*)g,
      (__attribute__((address_space(3))) void*)l, 16, 0, 0);
}

// fp32 -> bf16 cast, 4 elements/thread, vectorized.
__global__ __launch_bounds__(256) void cast_f32_bf16(
    const float* __restrict__ in, __hip_bfloat16* __restrict__ out, int n4)
{
  int i = blockIdx.x * 256 + threadIdx.x;
  if (i >= n4) return;
  float4 v = ((const float4*)in)[i];
  __hip_bfloat16 tmp[4] = {__float2bfloat16(v.x), __float2bfloat16(v.y),
                           __float2bfloat16(v.z), __float2bfloat16(v.w)};
  ((short4_t*)out)[i] = *(const short4_t*)tmp;
}

__device__ __forceinline__ void store_out(__hip_bfloat16* p, float v) { *p = __float2bfloat16(v); }
__device__ __forceinline__ void store_out(float* p, float v) { *p = v; }

// C (MxN) = A (MxK, row-major) * B^T  (B given NxK row-major). bf16 in, fp32 accum.
template <typename OutT>
__global__ __launch_bounds__(256) void gemm_bt(
    const __hip_bfloat16* __restrict__ A,
    const __hip_bfloat16* __restrict__ Bm,
    OutT* __restrict__ Cm,
    int K, int N)
{
  __shared__ __align__(16) __hip_bfloat16 As[128 * 32];
  __shared__ __align__(16) __hip_bfloat16 Bs[128 * 32];
  const int tid  = threadIdx.x;
  const int wave = tid >> 6;
  const int lane = tid & 63;
  const int quad = lane >> 4;
  const int l16  = lane & 15;
  const int bm = blockIdx.y * 128;
  const int bn = blockIdx.x * 128;
  const int wm = (wave >> 1) * 64;
  const int wn = (wave & 1) * 64;

  f32x4 acc[4][4];
#pragma unroll
  for (int i = 0; i < 4; i++)
#pragma unroll
    for (int j = 0; j < 4; j++)
#pragma unroll
      for (int r = 0; r < 4; r++) acc[i][j][r] = 0.f;

  const int srow = lane >> 2;
  const int scol = (lane & 3) * 8;

  for (int k0 = 0; k0 < K; k0 += 32) {
#pragma unroll
    for (int c = 0; c < 2; c++) {
      int r0 = (wave * 2 + c) * 16;
      gload_lds16(A  + (size_t)(bm + r0 + srow) * K + k0 + scol, As + r0 * 32);
      gload_lds16(Bm + (size_t)(bn + r0 + srow) * K + k0 + scol, Bs + r0 * 32);
    }
    __syncthreads();
    short8 af[4], bf[4];
#pragma unroll
    for (int i = 0; i < 4; i++)
      af[i] = *(const short8*)(As + (wm + i * 16 + l16) * 32 + quad * 8);
#pragma unroll
    for (int j = 0; j < 4; j++)
      bf[j] = *(const short8*)(Bs + (wn + j * 16 + l16) * 32 + quad * 8);
#pragma unroll
    for (int i = 0; i < 4; i++)
#pragma unroll
      for (int j = 0; j < 4; j++)
        acc[i][j] = __builtin_amdgcn_mfma_f32_16x16x32_bf16(af[i], bf[j], acc[i][j], 0, 0, 0);
    __syncthreads();
  }

#pragma unroll
  for (int i = 0; i < 4; i++)
#pragma unroll
    for (int j = 0; j < 4; j++)
#pragma unroll
      for (int r = 0; r < 4; r++) {
        int gm = bm + wm + i * 16 + quad * 4 + r;
        int gn = bn + wn + j * 16 + l16;
        store_out(Cm + (size_t)gm * N + gn, acc[i][j][r]);
      }
}

// In-place RoPE on q,k halves of qkv. Q half additionally pre-scaled by 1/sqrt(D)
// so the flash kernel needs no per-score multiply.
__global__ __launch_bounds__(256) void rope_qk(__hip_bfloat16* __restrict__ qkv)
{
  int tid = blockIdx.x * 256 + threadIdx.x;
  int d = tid & 63;
  int h = (tid >> 6) & 15;
  int t = (tid >> 10) & 2047;
  int bw = tid >> 21;
  int b = bw & 1, which = bw >> 1;
  size_t base = (size_t)(b * Tt + t) * Ff + which * 2048 + h * Dd + d;
  float inv = expf(-(float)d * (9.210340371976184f / 64.0f));
  float ang = (float)t * inv;
  float c = cosf(ang), s = sinf(ang);
  float x1 = __bfloat162float(qkv[base]);
  float x2 = __bfloat162float(qkv[base + 64]);
  float o1 = x1 * c - x2 * s;
  float o2 = x2 * c + x1 * s;
  if (which == 0) {  // q: fold in softmax scale
    o1 *= 0.08838834764831845f;
    o2 *= 0.08838834764831845f;
  }
  qkv[base]      = __float2bfloat16(o1);
  qkv[base + 64] = __float2bfloat16(o2);
}

// v (from qkv buffer, (b,t,h,d)) -> vt (b,h,d,t).
__global__ __launch_bounds__(256) void transpose_v(
    const __hip_bfloat16* __restrict__ qkv, __hip_bfloat16* __restrict__ vt)
{
  __shared__ __hip_bfloat16 tile[64 * 65];
  int bh = blockIdx.y;
  int dt = blockIdx.x >> 5;
  int tt = blockIdx.x & 31;
  int b = bh >> 4, h = bh & 15;
  const __hip_bfloat16* src = qkv + (size_t)(b * Tt + tt * 64) * Ff + 4096 + h * Dd + dt * 64;
#pragma unroll
  for (int i = 0; i < 16; i++) {
    int lin = i * 256 + threadIdx.x;
    int tl = lin >> 6, dc = lin & 63;
    tile[tl * 65 + dc] = src[(size_t)tl * Ff + dc];
  }
  __syncthreads();
  __hip_bfloat16* dst = vt + ((size_t)bh * Dd + dt * 64) * Tt + tt * 64;
#pragma unroll
  for (int i = 0; i < 16; i++) {
    int lin = i * 256 + threadIdx.x;
    int dr = lin >> 6, tc = lin & 63;
    dst[(size_t)dr * Tt + tc] = tile[tc * 65 + dr];
  }
}

// Flash attention v3: 512 threads (8 waves, 16 q-rows each -> 2 waves/SIMD for
// latency hiding), 128-row Q tiles, paired causal scheduling {p, 15-p},
// software-pipelined staging with raw s_barrier + manual vmcnt.
// LDS: Ks dbuf 32K + Vs 16K + Ps 17K = 66560 B.
__global__ __launch_bounds__(512) void flash_attn3(
    const __hip_bfloat16* __restrict__ qkv,
    const __hip_bfloat16* __restrict__ vt,
    __hip_bfloat16* __restrict__ yat)
{
  __shared__ __align__(16) __hip_bfloat16 KsBuf[2][8192];
  __shared__ __align__(16) __hip_bfloat16 VsBuf[8192];
  __shared__ __align__(16) __hip_bfloat16 PsBuf[8 * 1088];
  const int tid  = threadIdx.x;
  const int wave = tid >> 6;          // 0..7
  const int lane = tid & 63;
  const int quad = lane >> 4;
  const int l16  = lane & 15;
  const int bh    = blockIdx.x & 31;
  const int pairp = blockIdx.x >> 5;  // 0..7
  const int b = bh >> 4, h = bh & 15;

  const char* kbase = (const char*)(qkv + (size_t)b * Tt * Ff + 2048 + h * Dd);
  const char* vbase = (const char*)(vt + (size_t)bh * Dd * Tt);
  __hip_bfloat16* Pw = PsBuf + wave * 1088;
  const int srow = lane & 15;   // staging: row within 16-row group
  const int scol = lane >> 4;   // staging: 16B sub-column

#pragma unroll 1
  for (int half = 0; half < 2; ++half) {
    const int qi = half ? (15 - pairp) : pairp;
    const int qm0 = qi * 128;
    const int niter = 2 * qi + 2;

    // Q fragments: this wave's 16 rows (Q pre-scaled by 1/sqrt(D) in rope_qk)
    short8 qf[4];
    {
      const __hip_bfloat16* qrow =
          qkv + (size_t)(b * Tt + qm0 + wave * 16 + l16) * Ff + h * Dd;
#pragma unroll
      for (int kc = 0; kc < 4; kc++)
        qf[kc] = *(const short8*)(qrow + kc * 32 + quad * 8);
    }

    // stage K(0) -> buf 0 (granule order: chunk*512 + lane*8 elems)
#pragma unroll
    for (int c = 0; c < 2; c++) {
      int chunk = wave * 2 + c;
      int j = chunk >> 2, kc = chunk & 3;
      const char* src = kbase + (size_t)(j * 16 + srow) * (Ff * 2) + kc * 64 + scol * 16;
      gload_lds16(src, KsBuf[0] + chunk * 512);
    }

    f32x4 oacc[8];
#pragma unroll
    for (int jd = 0; jd < 8; jd++)
#pragma unroll
      for (int r = 0; r < 4; r++) oacc[jd][r] = 0.f;
    float mrow[4], lrow[4];
#pragma unroll
    for (int r = 0; r < 4; r++) { mrow[r] = -INFINITY; lrow[r] = 0.f; }

#pragma unroll 1
    for (int kt = 0; kt < niter; ++kt) {
      __builtin_amdgcn_s_barrier();                      // A: prev iter fully done
      // stage V(kt) -> Vs (single buffer; safe after barrier A)
#pragma unroll
      for (int c = 0; c < 2; c++) {
        int chunk = wave * 2 + c;
        int jd = chunk >> 1, k2 = chunk & 1;
        const char* src = vbase + (size_t)(jd * 16 + srow) * (Tt * 2) + kt * 128 + k2 * 64 + scol * 16;
        gload_lds16(src, VsBuf + chunk * 512);
      }
      if (kt + 1 < niter) {
        // stage K(kt+1) -> other buf
#pragma unroll
        for (int c = 0; c < 2; c++) {
          int chunk = wave * 2 + c;
          int j = chunk >> 2, kc = chunk & 3;
          const char* src = kbase + (size_t)((kt + 1) * 64 + j * 16 + srow) * (Ff * 2) + kc * 64 + scol * 16;
          gload_lds16(src, KsBuf[(kt + 1) & 1] + chunk * 512);
        }
        __builtin_amdgcn_s_waitcnt(0xF74);  // vmcnt(4): K(kt) landed (V(kt)+K(kt+1) in flight)
      } else {
        __builtin_amdgcn_s_waitcnt(0xF72);  // vmcnt(2): K(kt) landed (V(kt) in flight)
      }
      __builtin_amdgcn_s_barrier();                      // B: K(kt) visible to all waves

      const __hip_bfloat16* KsB = KsBuf[kt & 1];
      const bool diag = (kt >= 2 * qi);

      // S = Q K^T : 16 rows x 64 cols
      f32x4 sacc[4];
#pragma unroll
      for (int j = 0; j < 4; j++)
#pragma unroll
        for (int r = 0; r < 4; r++) sacc[j][r] = 0.f;
#pragma unroll
      for (int j = 0; j < 4; j++)
#pragma unroll
        for (int kc = 0; kc < 4; kc++) {
          short8 kf = *(const short8*)(KsB + (j * 4 + kc) * 512 + lane * 8);
          sacc[j] = __builtin_amdgcn_mfma_f32_16x16x32_bf16(qf[kc], kf, sacc[j], 0, 0, 0);
        }
      float sv[4][4];
#pragma unroll
      for (int j = 0; j < 4; j++)
#pragma unroll
        for (int r = 0; r < 4; r++) {
          float v = sacc[j][r];
          if (diag) {
            int kg = kt * 64 + j * 16 + l16;
            int qg = qm0 + wave * 16 + quad * 4 + r;
            if (kg > qg) v = -INFINITY;
          }
          sv[j][r] = v;
        }
      float mnew[4];
#pragma unroll
      for (int r = 0; r < 4; r++)
        mnew[r] = fmaxf(fmaxf(sv[0][r], sv[1][r]), fmaxf(sv[2][r], sv[3][r]));
#pragma unroll
      for (int off = 1; off < 16; off <<= 1)
#pragma unroll
        for (int r = 0; r < 4; r++)
          mnew[r] = fmaxf(mnew[r], __shfl_xor(mnew[r], off, 64));
      float alpha[4];
#pragma unroll
      for (int r = 0; r < 4; r++) {
        float mi = fmaxf(mrow[r], mnew[r]);
        alpha[r] = __expf(mrow[r] - mi);
        mrow[r] = mi;
      }
      float rs[4] = {0.f, 0.f, 0.f, 0.f};
#pragma unroll
      for (int j = 0; j < 4; j++)
#pragma unroll
        for (int r = 0; r < 4; r++) {
          float p = __expf(sv[j][r] - mrow[r]);
          rs[r] += p;
          Pw[(j * 2 + (l16 >> 3)) * 136 + (quad * 4 + r) * 8 + (l16 & 7)] = __float2bfloat16(p);
        }
#pragma unroll
      for (int off = 1; off < 16; off <<= 1)
#pragma unroll
        for (int r = 0; r < 4; r++)
          rs[r] += __shfl_xor(rs[r], off, 64);
#pragma unroll
      for (int r = 0; r < 4; r++) lrow[r] = lrow[r] * alpha[r] + rs[r];
#pragma unroll
      for (int jd = 0; jd < 8; jd++)
#pragma unroll
        for (int r = 0; r < 4; r++) oacc[jd][r] *= alpha[r];

      if (kt + 1 < niter) {
        __builtin_amdgcn_s_waitcnt(0xF72);  // vmcnt(2): V(kt) landed (K(kt+1) in flight)
      } else {
        __builtin_amdgcn_s_waitcnt(0xF70);  // vmcnt(0)
      }
      __builtin_amdgcn_s_barrier();                      // C: V(kt) visible to all waves

      // O += P V
#pragma unroll
      for (int k2 = 0; k2 < 2; k2++) {
        short8 pf = *(const short8*)(Pw + (k2 * 4 + quad) * 136 + l16 * 8);
#pragma unroll
        for (int jd = 0; jd < 8; jd++) {
          short8 vf = *(const short8*)(VsBuf + (jd * 2 + k2) * 512 + lane * 8);
          oacc[jd] = __builtin_amdgcn_mfma_f32_16x16x32_bf16(pf, vf, oacc[jd], 0, 0, 0);
        }
      }
    }

    // epilogue: O / l -> yat
    float linv[4];
#pragma unroll
    for (int r = 0; r < 4; r++) linv[r] = 1.f / lrow[r];
#pragma unroll
    for (int jd = 0; jd < 8; jd++)
#pragma unroll
      for (int r = 0; r < 4; r++) {
        int trow = qm0 + wave * 16 + quad * 4 + r;
        yat[(size_t)(b * Tt + trow) * Cc + h * Dd + jd * 16 + l16] =
            __float2bfloat16(oacc[jd][r] * linv[r]);
      }
  }
}

extern "C" void kernel_launch(void* const* d_in, const int* in_sizes, int n_in,
                              void* d_out, int out_size, void* d_ws, size_t ws_size,
                              hipStream_t stream) {
  (void)in_sizes; (void)n_in; (void)out_size; (void)ws_size;
  const float* x_f      = (const float*)d_in[0];
  const float* w_qkv_f  = (const float*)d_in[1];
  const float* w_proj_f = (const float*)d_in[2];
  float* out = (float*)d_out;

  char* ws = (char*)d_ws;
  __hip_bfloat16* qkv = (__hip_bfloat16*)ws;                      // 48 MiB
  __hip_bfloat16* vt  = (__hip_bfloat16*)(ws + 50331648);         // 16 MiB
  __hip_bfloat16* yat = (__hip_bfloat16*)(ws + 67108864);         // 16 MiB
  __hip_bfloat16* xb  = (__hip_bfloat16*)(ws + 83886080);         // 16 MiB
  __hip_bfloat16* wqb = (__hip_bfloat16*)(ws + 100663296);        // 24 MiB
  __hip_bfloat16* wpb = (__hip_bfloat16*)(ws + 125829120);        // 8 MiB

  cast_f32_bf16<<<8192, 256, 0, stream>>>(x_f, xb, 2097152);
  cast_f32_bf16<<<12288, 256, 0, stream>>>(w_qkv_f, wqb, 3145728);
  cast_f32_bf16<<<4096, 256, 0, stream>>>(w_proj_f, wpb, 1048576);

  gemm_bt<__hip_bfloat16><<<dim3(48, 32), 256, 0, stream>>>(xb, wqb, qkv, 2048, 6144);
  rope_qk<<<32768, 256, 0, stream>>>(qkv);
  transpose_v<<<dim3(64, 32), 256, 0, stream>>>(qkv, vt);
  flash_attn3<<<256, 512, 0, stream>>>(qkv, vt, yat);
  gemm_bt<float><<<dim3(16, 32), 256, 0, stream>>>(yat, wpb, out, 2048, 2048);
}